// Round 1
// baseline (82.046 us; speedup 1.0000x reference)
//
#include <hip/hip_runtime.h>
#include <math.h>

#define BB 4
#define RR 64
#define SS 512
#define HH 768
#define EE 64
#define SEGD 128
#define NT 6
#define NC 13
#define NP 3
#define NO (NT + NC + NP)   // 22
#define REP 2560            // 2*H + 2*SEG + H

__global__ __launch_bounds__(256)
void rel_cls_kernel(const float* __restrict__ hidden,     // [B,S,H]
                    const int*   __restrict__ rel_pairs,  // [B,R,2]
                    const int*   __restrict__ rel_masks,  // [B,R,S]
                    const float* __restrict__ span,       // [B,E,H]
                    const float* __restrict__ segs,       // [B,E,SEG]
                    const float* __restrict__ Wt, const float* __restrict__ bt,
                    const float* __restrict__ Wc, const float* __restrict__ bc,
                    const float* __restrict__ Wp, const float* __restrict__ bp,
                    float* __restrict__ out)
{
    const int br = blockIdx.x;          // 0 .. B*R-1
    const int b  = br / RR;
    const int t  = threadIdx.x;         // 0 .. 255

    __shared__ int   smask[SS];         // 2 KB
    __shared__ float feat[REP];         // 10 KB
    __shared__ float red[4][NO];        // 352 B

    // ---- load mask into LDS (coalesced) ----
    const int* mrow = rel_masks + (size_t)br * SS;
    smask[t]       = mrow[t];
    smask[t + 256] = mrow[t + 256];

    // ---- gather pair span / seg embeddings into feature vector ----
    const int i0 = rel_pairs[(size_t)br * 2 + 0];
    const int i1 = rel_pairs[(size_t)br * 2 + 1];
    const float* sp0 = span + ((size_t)b * EE + i0) * HH;
    const float* sp1 = span + ((size_t)b * EE + i1) * HH;
    feat[t]             = sp0[t];
    feat[t + 256]       = sp0[t + 256];
    feat[t + 512]       = sp0[t + 512];
    feat[HH + t]        = sp1[t];
    feat[HH + t + 256]  = sp1[t + 256];
    feat[HH + t + 512]  = sp1[t + 512];
    const float* sg0 = segs + ((size_t)b * EE + i0) * SEGD;
    const float* sg1 = segs + ((size_t)b * EE + i1) * SEGD;
    if (t < SEGD) feat[2 * HH + t]        = sg0[t];
    else          feat[2 * HH + SEGD + (t - SEGD)] = sg1[t - SEGD];
    __syncthreads();

    // ---- masked max over sequence: thread t owns h = t, t+256, t+512 ----
    float m0 = -INFINITY, m1 = -INFINITY, m2 = -INFINITY;
    bool any = false;
    for (int s = 0; s < SS; ++s) {
        if (smask[s] != 0) {            // wave-uniform branch
            any = true;
            const float* hp = hidden + ((size_t)b * SS + s) * HH;
            m0 = fmaxf(m0, hp[t]);
            m1 = fmaxf(m1, hp[t + 256]);
            m2 = fmaxf(m2, hp[t + 512]);
        }
    }
    if (!any) { m0 = 0.f; m1 = 0.f; m2 = 0.f; }
    const int CTX0 = 2 * HH + 2 * SEGD;   // 1792
    feat[CTX0 + t]       = m0;
    feat[CTX0 + t + 256] = m1;
    feat[CTX0 + t + 512] = m2;
    __syncthreads();

    // ---- 2560 x 22 matvec: per-thread partials over strided feature idx ----
    float acc[NO];
#pragma unroll
    for (int o = 0; o < NO; ++o) acc[o] = 0.f;

    for (int f = t; f < REP; f += 256) {
        const float fv = feat[f];
        const float* wt = Wt + (size_t)f * NT;
        const float* wc = Wc + (size_t)f * NC;
        const float* wp = Wp + (size_t)f * NP;
#pragma unroll
        for (int o = 0; o < NT; ++o) acc[o]            += fv * wt[o];
#pragma unroll
        for (int o = 0; o < NC; ++o) acc[NT + o]       += fv * wc[o];
#pragma unroll
        for (int o = 0; o < NP; ++o) acc[NT + NC + o]  += fv * wp[o];
    }

    // ---- reduce: shuffle within each 64-lane wave ----
#pragma unroll
    for (int o = 0; o < NO; ++o) {
#pragma unroll
        for (int off = 32; off > 0; off >>= 1)
            acc[o] += __shfl_down(acc[o], off, 64);
    }
    const int wid  = t >> 6;
    const int lane = t & 63;
    if (lane == 0) {
#pragma unroll
        for (int o = 0; o < NO; ++o) red[wid][o] = acc[o];
    }
    __syncthreads();

    // ---- final: add bias, write ----
    if (t < NO) {
        const float v = red[0][t] + red[1][t] + red[2][t] + red[3][t];
        if (t < NT) {
            out[(size_t)br * NT + t] = v + bt[t];
        } else if (t < NT + NC) {
            const int o = t - NT;
            out[(size_t)BB * RR * NT + (size_t)br * NC + o] = v + bc[o];
        } else {
            const int o = t - NT - NC;
            out[(size_t)BB * RR * (NT + NC) + (size_t)br * NP + o] = v + bp[o];
        }
    }
}

extern "C" void kernel_launch(void* const* d_in, const int* in_sizes, int n_in,
                              void* d_out, int out_size, void* d_ws, size_t ws_size,
                              hipStream_t stream) {
    const float* hidden = (const float*)d_in[0];
    const int*   pairs  = (const int*)d_in[1];
    const int*   masks  = (const int*)d_in[2];
    // d_in[3] = rel_sizes (unused by reference)
    const float* span   = (const float*)d_in[4];
    const float* segs   = (const float*)d_in[5];
    const float* Wt     = (const float*)d_in[6];
    const float* bt     = (const float*)d_in[7];
    const float* Wc     = (const float*)d_in[8];
    const float* bc     = (const float*)d_in[9];
    const float* Wp     = (const float*)d_in[10];
    const float* bp     = (const float*)d_in[11];
    float* out = (float*)d_out;

    dim3 grid(BB * RR);
    dim3 block(256);
    hipLaunchKernelGGL(rel_cls_kernel, grid, block, 0, stream,
                       hidden, pairs, masks, span, segs,
                       Wt, bt, Wc, bc, Wp, bp, out);
}

// Round 2
// 28.390 us; speedup vs baseline: 2.8900x; 2.8900x over previous
//
#include <hip/hip_runtime.h>
#include <math.h>

#define BB 4
#define RR 64
#define SS 512
#define HH 768
#define EE 64
#define SEGD 128
#define NT 6
#define NC 13
#define NP 3
#define NO (NT + NC + NP)   // 22
#define REP 2560            // 2*H + 2*SEG + H
#define RPG 8               // relations per phase-1 block
#define NGRP (RR / RPG)     // 8 groups
#define NEGV -1e30f

// ---------------- phase 1: branchless masked max, 8 rels/block ----------------
__global__ __launch_bounds__(256)
void p1_maxctx(const float* __restrict__ hidden,     // [B,S,H]
               const int*   __restrict__ rel_masks,  // [B,R,S]
               float* __restrict__ ws,               // [B*R, SC, H] partial maxes
               int SC)
{
    const int bid  = blockIdx.x;              // b * NGRP * SC + grp * SC + sc
    const int sc   = bid % SC;
    const int grp  = (bid / SC) % NGRP;
    const int b    = bid / (SC * NGRP);
    const int t    = threadIdx.x;
    const int rows = SS / SC;
    const int s0   = sc * rows;
    const int r0   = grp * RPG;

    __shared__ float sadd[RPG * SS];          // addend per (rel, row); <=16KB used

    for (int i = t; i < RPG * rows; i += 256) {
        const int r = i / rows;
        const int s = i - r * rows;
        const int mv = rel_masks[((size_t)(b * RR + r0 + r)) * SS + s0 + s];
        sadd[r * rows + s] = mv ? 0.f : NEGV;
    }
    __syncthreads();

    float m[RPG][3];
#pragma unroll
    for (int r = 0; r < RPG; ++r) { m[r][0] = -INFINITY; m[r][1] = -INFINITY; m[r][2] = -INFINITY; }

#pragma unroll 2
    for (int s = 0; s < rows; ++s) {
        const float* hp = hidden + ((size_t)(b * SS + s0 + s)) * HH;
        const float v0 = hp[t];
        const float v1 = hp[t + 256];
        const float v2 = hp[t + 512];
#pragma unroll
        for (int r = 0; r < RPG; ++r) {
            const float a = sadd[r * rows + s];
            m[r][0] = fmaxf(m[r][0], v0 + a);
            m[r][1] = fmaxf(m[r][1], v1 + a);
            m[r][2] = fmaxf(m[r][2], v2 + a);
        }
    }

#pragma unroll
    for (int r = 0; r < RPG; ++r) {
        float* wp = ws + (((size_t)(b * RR + r0 + r) * SC) + sc) * HH;
        wp[t]       = m[r][0];
        wp[t + 256] = m[r][1];
        wp[t + 512] = m[r][2];
    }
}

// ---------------- phase 2: reduce partials, gather, matvec ----------------
__global__ __launch_bounds__(256)
void p2_head(const float* __restrict__ ws,          // [B*R, SC, H]
             const int*   __restrict__ rel_pairs,   // [B,R,2]
             const float* __restrict__ span,        // [B,E,H]
             const float* __restrict__ segs,        // [B,E,SEG]
             const float* __restrict__ Wt, const float* __restrict__ bt,
             const float* __restrict__ Wc, const float* __restrict__ bc,
             const float* __restrict__ Wp, const float* __restrict__ bp,
             float* __restrict__ out, int SC)
{
    const int br = blockIdx.x;
    const int b  = br / RR;
    const int t  = threadIdx.x;

    __shared__ float feat[REP];
    __shared__ float red[4][NO];

    // gather pair span / seg embeddings
    const int i0 = rel_pairs[(size_t)br * 2 + 0];
    const int i1 = rel_pairs[(size_t)br * 2 + 1];
    const float* sp0 = span + ((size_t)b * EE + i0) * HH;
    const float* sp1 = span + ((size_t)b * EE + i1) * HH;
    feat[t]            = sp0[t];
    feat[t + 256]      = sp0[t + 256];
    feat[t + 512]      = sp0[t + 512];
    feat[HH + t]       = sp1[t];
    feat[HH + t + 256] = sp1[t + 256];
    feat[HH + t + 512] = sp1[t + 512];
    const float* sg0 = segs + ((size_t)b * EE + i0) * SEGD;
    const float* sg1 = segs + ((size_t)b * EE + i1) * SEGD;
    if (t < SEGD) feat[2 * HH + t] = sg0[t];
    else          feat[2 * HH + SEGD + (t - SEGD)] = sg1[t - SEGD];

    // reduce SC partial maxes
    float m0 = -INFINITY, m1 = -INFINITY, m2 = -INFINITY;
    for (int c = 0; c < SC; ++c) {
        const float* wp = ws + ((size_t)br * SC + c) * HH;
        m0 = fmaxf(m0, wp[t]);
        m1 = fmaxf(m1, wp[t + 256]);
        m2 = fmaxf(m2, wp[t + 512]);
    }
    // all-masked rows collapse to ~-1e30; reference zeroes them
    if (m0 < -1e29f) m0 = 0.f;
    if (m1 < -1e29f) m1 = 0.f;
    if (m2 < -1e29f) m2 = 0.f;
    const int CTX0 = 2 * HH + 2 * SEGD;   // 1792
    feat[CTX0 + t]       = m0;
    feat[CTX0 + t + 256] = m1;
    feat[CTX0 + t + 512] = m2;
    __syncthreads();

    // 2560 x 22 matvec
    float acc[NO];
#pragma unroll
    for (int o = 0; o < NO; ++o) acc[o] = 0.f;
    for (int f = t; f < REP; f += 256) {
        const float fv = feat[f];
        const float* wt = Wt + (size_t)f * NT;
        const float* wc = Wc + (size_t)f * NC;
        const float* wp = Wp + (size_t)f * NP;
#pragma unroll
        for (int o = 0; o < NT; ++o) acc[o]           += fv * wt[o];
#pragma unroll
        for (int o = 0; o < NC; ++o) acc[NT + o]      += fv * wc[o];
#pragma unroll
        for (int o = 0; o < NP; ++o) acc[NT + NC + o] += fv * wp[o];
    }
#pragma unroll
    for (int o = 0; o < NO; ++o) {
#pragma unroll
        for (int off = 32; off > 0; off >>= 1)
            acc[o] += __shfl_down(acc[o], off, 64);
    }
    const int wid  = t >> 6;
    const int lane = t & 63;
    if (lane == 0) {
#pragma unroll
        for (int o = 0; o < NO; ++o) red[wid][o] = acc[o];
    }
    __syncthreads();

    if (t < NO) {
        const float v = red[0][t] + red[1][t] + red[2][t] + red[3][t];
        if (t < NT) {
            out[(size_t)br * NT + t] = v + bt[t];
        } else if (t < NT + NC) {
            const int o = t - NT;
            out[(size_t)BB * RR * NT + (size_t)br * NC + o] = v + bc[o];
        } else {
            const int o = t - NT - NC;
            out[(size_t)BB * RR * (NT + NC) + (size_t)br * NP + o] = v + bp[o];
        }
    }
}

// ---------------- fallback: round-1 fused kernel (if ws too small) ----------------
__global__ __launch_bounds__(256)
void rel_cls_fused(const float* __restrict__ hidden,
                   const int*   __restrict__ rel_pairs,
                   const int*   __restrict__ rel_masks,
                   const float* __restrict__ span,
                   const float* __restrict__ segs,
                   const float* __restrict__ Wt, const float* __restrict__ bt,
                   const float* __restrict__ Wc, const float* __restrict__ bc,
                   const float* __restrict__ Wp, const float* __restrict__ bp,
                   float* __restrict__ out)
{
    const int br = blockIdx.x;
    const int b  = br / RR;
    const int t  = threadIdx.x;

    __shared__ float sadd[SS];
    __shared__ float feat[REP];
    __shared__ float red[4][NO];

    const int* mrow = rel_masks + (size_t)br * SS;
    sadd[t]       = mrow[t] ? 0.f : NEGV;
    sadd[t + 256] = mrow[t + 256] ? 0.f : NEGV;

    const int i0 = rel_pairs[(size_t)br * 2 + 0];
    const int i1 = rel_pairs[(size_t)br * 2 + 1];
    const float* sp0 = span + ((size_t)b * EE + i0) * HH;
    const float* sp1 = span + ((size_t)b * EE + i1) * HH;
    feat[t]            = sp0[t];
    feat[t + 256]      = sp0[t + 256];
    feat[t + 512]      = sp0[t + 512];
    feat[HH + t]       = sp1[t];
    feat[HH + t + 256] = sp1[t + 256];
    feat[HH + t + 512] = sp1[t + 512];
    const float* sg0 = segs + ((size_t)b * EE + i0) * SEGD;
    const float* sg1 = segs + ((size_t)b * EE + i1) * SEGD;
    if (t < SEGD) feat[2 * HH + t] = sg0[t];
    else          feat[2 * HH + SEGD + (t - SEGD)] = sg1[t - SEGD];
    __syncthreads();

    float m0 = -INFINITY, m1 = -INFINITY, m2 = -INFINITY;
#pragma unroll 4
    for (int s = 0; s < SS; ++s) {
        const float* hp = hidden + ((size_t)b * SS + s) * HH;
        const float a = sadd[s];
        m0 = fmaxf(m0, hp[t] + a);
        m1 = fmaxf(m1, hp[t + 256] + a);
        m2 = fmaxf(m2, hp[t + 512] + a);
    }
    if (m0 < -1e29f) m0 = 0.f;
    if (m1 < -1e29f) m1 = 0.f;
    if (m2 < -1e29f) m2 = 0.f;
    const int CTX0 = 2 * HH + 2 * SEGD;
    feat[CTX0 + t]       = m0;
    feat[CTX0 + t + 256] = m1;
    feat[CTX0 + t + 512] = m2;
    __syncthreads();

    float acc[NO];
#pragma unroll
    for (int o = 0; o < NO; ++o) acc[o] = 0.f;
    for (int f = t; f < REP; f += 256) {
        const float fv = feat[f];
        const float* wt = Wt + (size_t)f * NT;
        const float* wc = Wc + (size_t)f * NC;
        const float* wp = Wp + (size_t)f * NP;
#pragma unroll
        for (int o = 0; o < NT; ++o) acc[o]           += fv * wt[o];
#pragma unroll
        for (int o = 0; o < NC; ++o) acc[NT + o]      += fv * wc[o];
#pragma unroll
        for (int o = 0; o < NP; ++o) acc[NT + NC + o] += fv * wp[o];
    }
#pragma unroll
    for (int o = 0; o < NO; ++o) {
#pragma unroll
        for (int off = 32; off > 0; off >>= 1)
            acc[o] += __shfl_down(acc[o], off, 64);
    }
    const int wid  = t >> 6;
    const int lane = t & 63;
    if (lane == 0) {
#pragma unroll
        for (int o = 0; o < NO; ++o) red[wid][o] = acc[o];
    }
    __syncthreads();

    if (t < NO) {
        const float v = red[0][t] + red[1][t] + red[2][t] + red[3][t];
        if (t < NT) {
            out[(size_t)br * NT + t] = v + bt[t];
        } else if (t < NT + NC) {
            const int o = t - NT;
            out[(size_t)BB * RR * NT + (size_t)br * NC + o] = v + bc[o];
        } else {
            const int o = t - NT - NC;
            out[(size_t)BB * RR * (NT + NC) + (size_t)br * NP + o] = v + bp[o];
        }
    }
}

extern "C" void kernel_launch(void* const* d_in, const int* in_sizes, int n_in,
                              void* d_out, int out_size, void* d_ws, size_t ws_size,
                              hipStream_t stream) {
    const float* hidden = (const float*)d_in[0];
    const int*   pairs  = (const int*)d_in[1];
    const int*   masks  = (const int*)d_in[2];
    const float* span   = (const float*)d_in[4];
    const float* segs   = (const float*)d_in[5];
    const float* Wt     = (const float*)d_in[6];
    const float* bt     = (const float*)d_in[7];
    const float* Wc     = (const float*)d_in[8];
    const float* bc     = (const float*)d_in[9];
    const float* Wp     = (const float*)d_in[10];
    const float* bp     = (const float*)d_in[11];
    float* out = (float*)d_out;

    const size_t slot = (size_t)BB * RR * HH * sizeof(float);  // 786 KB per chunk
    int SC = 0;
    for (int c = 16; c >= 1; c >>= 1) {
        if ((size_t)c * slot <= ws_size) { SC = c; break; }
    }

    if (SC >= 1) {
        float* ws = (float*)d_ws;
        dim3 g1(BB * NGRP * SC), blk(256);
        hipLaunchKernelGGL(p1_maxctx, g1, blk, 0, stream, hidden, masks, ws, SC);
        dim3 g2(BB * RR);
        hipLaunchKernelGGL(p2_head, g2, blk, 0, stream, ws, pairs, span, segs,
                           Wt, bt, Wc, bc, Wp, bp, out, SC);
    } else {
        dim3 grid(BB * RR), blk(256);
        hipLaunchKernelGGL(rel_cls_fused, grid, blk, 0, stream,
                           hidden, pairs, masks, span, segs,
                           Wt, bt, Wc, bc, Wp, bp, out);
    }
}